// Round 12
// baseline (369.742 us; speedup 1.0000x reference)
//
#include <hip/hip_runtime.h>
#include <hip/hip_bf16.h>
#include <math.h>

typedef __hip_bfloat16 bf16;
typedef __bf16 bf16x8 __attribute__((ext_vector_type(8)));
typedef float f32x4 __attribute__((ext_vector_type(4)));
typedef float f32x4v __attribute__((ext_vector_type(4)));
typedef unsigned short u16x8v __attribute__((ext_vector_type(8)));
typedef unsigned short u16x4v __attribute__((ext_vector_type(4)));

#define AS1 __attribute__((address_space(1)))
#define AS3 __attribute__((address_space(3)))

// Problem constants
#define BB 4
#define TT 4096
#define DD 1024

__device__ __forceinline__ float fast_sigmoid(float x) {
  return 1.0f / (1.0f + __expf(-x));
}
__device__ __forceinline__ float fast_tanh(float x) {
  return 2.0f / (1.0f + __expf(-2.0f * x)) - 1.0f;
}
__device__ __forceinline__ float b2f(unsigned short u) {
  union { unsigned int i; float f; } x;
  x.i = ((unsigned int)u) << 16;
  return x.f;
}
__device__ __forceinline__ unsigned short f2b(float f) {
  union { bf16 h; unsigned short u; } x;
  x.h = __float2bfloat16(f);
  return x.u;
}

// ---------------------------------------------------------------------------
// Weight fp32 -> bf16
// ---------------------------------------------------------------------------
__global__ __launch_bounds__(256) void w2bf_kernel(const float* __restrict__ w,
                                                   bf16* __restrict__ o,
                                                   int n) {
  int i = blockIdx.x * 256 + threadIdx.x;
  if (i < n) o[i] = __float2bfloat16(w[i]);
}

// ---------------------------------------------------------------------------
// conv + add -> bf16, 4 channels / thread
// ---------------------------------------------------------------------------
__global__ __launch_bounds__(256) void conv_add_kernel(
    const float* __restrict__ x, const float* __restrict__ Wc,
    bf16* __restrict__ xm, int total4) {
  int i = blockIdx.x * 256 + threadIdx.x;
  if (i >= total4) return;
  int c4 = (i & (DD / 4 - 1)) * 4;
  int t = (i / (DD / 4)) % TT;
  size_t base = (size_t)i * 4;
  f32x4v x0 = *(const f32x4v*)(x + base);
  f32x4v p1 = (t >= 1) ? *(const f32x4v*)(x + base - DD) : (f32x4v)0.0f;
  f32x4v p2 = (t >= 2) ? *(const f32x4v*)(x + base - 2 * DD) : (f32x4v)0.0f;
  f32x4v p3 = (t >= 3) ? *(const f32x4v*)(x + base - 3 * DD) : (f32x4v)0.0f;
  u16x4v o;
#pragma unroll
  for (int j = 0; j < 4; ++j) {
    f32x4v w = *(const f32x4v*)(Wc + (size_t)(c4 + j) * 4);
    float acc = x0[j] + w[3] * x0[j] + w[2] * p1[j] + w[1] * p2[j] +
                w[0] * p3[j];
    o[j] = f2b(acc);
  }
  *(u16x4v*)(xm + base) = o;
}

// ---------------------------------------------------------------------------
// 128x128 MFMA GEMM, BK=32, 4 waves (2Mx2N), TRIPLE-buffered 48 KiB LDS,
// lead-2 prefetch, ONE barrier per phase, r10-verified 0-conflict swizzle.
// L2-aware 2D supertile traversal per XCD: 4 bm x 8 bn supertiles keep the
// resident working set (1 MB A + 2 MB B) inside the 4 MiB per-XCD L2
// (r10 FETCH=98.5MB vs ~40MB ideal -> staging was HBM-latency class).
// Phase p: {stage(p+2)->slot[(p+2)%3] (4 gll) | 8 ds_read from slot[p%3] |
// 16 MFMA | vmcnt(4) gate (stage(p+1) landed) | barrier}.
// Hazards: stage(p+2) overwrites slot[(p-1)%3] whose readers passed the
// end-of-(p-1) barrier; reads of slot[p] gated by end-of-(p-1) vmcnt+barrier.
// Swizzle (0 conflicts measured r10):
//   stage: lane l -> row l>>2, phys slot l&3; source logical slot
//          (l&3)^((l>>3)&3)
//   read:  phys slot = (l>>4) ^ ((l>>1)&3)
// C[m][n] = sum_k A[m][k]*B[n][k]; bf16; K%64==0, M,N%128==0,
// (M/128)%32==0... requires mb8%4==0 and NB%8==0.
// EP=0: fp32 C. EP=1: bf16 C with per-1024-col activation.
// ---------------------------------------------------------------------------
template <int EP>
__global__ __launch_bounds__(256, 3) void gemm128_kernel(
    const bf16* __restrict__ A, const bf16* __restrict__ B,
    void* __restrict__ C, int M, int N, int K, int MB, int NB) {
  __shared__ __align__(16) bf16 As[3][128][32];
  __shared__ __align__(16) bf16 Bs[3][128][32];

  const int tid = threadIdx.x;
  const int wv = tid >> 6, l = tid & 63;
  const int wm = wv >> 1, wn = wv & 1;

  // XCD-chunked + 2D supertile (4 bm x 8 bn) mapping
  const int bid = blockIdx.x;
  const int xcd = bid & 7, ii = bid >> 3;
  const int mb8 = MB >> 3;        // m-blocks per XCD (mult of 4)
  const int nSm = mb8 >> 2;       // supertiles along m within XCD
  const int s = ii >> 5, r = ii & 31;
  const int sm = s % nSm, sn = s / nSm;
  const int bm = xcd * mb8 + sm * 4 + (r & 3);
  const int bn = sn * 8 + (r >> 2);
  const int m0 = bm * 128, n0 = bn * 128;

  // staging source (pre-swizzled, r10-verified)
  const int srow = l >> 2;
  const int scolE = ((l & 3) ^ ((l >> 3) & 3)) * 8;
  const bf16* Ab = A + (size_t)(m0 + wv * 32 + srow) * K + scolE;
  const bf16* Bb = B + (size_t)(n0 + wv * 32 + srow) * K + scolE;

  // frag-read constants
  const int l15 = l & 15;
  const int physColB = ((l >> 4) ^ ((l >> 1) & 3)) * 16;
  const char* AsB = (const char*)As;
  const char* BsB = (const char*)Bs;
  const int aBase = wm * 4096 + l15 * 64 + physColB;
  const int bBase = wn * 4096 + l15 * 64 + physColB;

  auto stageKt = [&](int kt, int slot) {
    const int k0 = kt * 32;
#pragma unroll
    for (int j = 0; j < 2; ++j) {
      __builtin_amdgcn_global_load_lds(
          (const AS1 void*)(Ab + (size_t)(j * 16) * K + k0),
          (AS3 void*)&As[slot][wv * 32 + j * 16][0], 16, 0, 0);
      __builtin_amdgcn_global_load_lds(
          (const AS1 void*)(Bb + (size_t)(j * 16) * K + k0),
          (AS3 void*)&Bs[slot][wv * 32 + j * 16][0], 16, 0, 0);
    }
  };

  f32x4 acc[4][4];
#pragma unroll
  for (int i = 0; i < 4; ++i)
#pragma unroll
    for (int j = 0; j < 4; ++j) acc[i][j] = (f32x4)0.0f;

  const int NT = K >> 5;

  // prologue: kt0 -> slot0, kt1 -> slot1; wait kt0; barrier
  stageKt(0, 0);
  stageKt(1, 1);
  asm volatile("s_waitcnt vmcnt(4)" ::: "memory");
  __builtin_amdgcn_sched_barrier(0);
  __builtin_amdgcn_s_barrier();

  bf16x8 aF[4], bF[4];
  int cur = 0;

#pragma unroll 1
  for (int p = 0; p < NT; ++p) {
    // stage(p+2) into slot[(p+2)%3]
    if (p + 2 < NT) {
      int s2 = cur + 2;
      if (s2 >= 3) s2 -= 3;
      stageKt(p + 2, s2);
    }
    // frag reads from slot[cur]
    const int cof = cur * 8192;
#pragma unroll
    for (int mi = 0; mi < 4; ++mi)
      aF[mi] = *(const bf16x8*)(AsB + cof + aBase + mi * 1024);
#pragma unroll
    for (int nj = 0; nj < 4; ++nj)
      bF[nj] = *(const bf16x8*)(BsB + cof + bBase + nj * 1024);
    __builtin_amdgcn_s_setprio(1);
#pragma unroll
    for (int mi = 0; mi < 4; ++mi)
#pragma unroll
      for (int nj = 0; nj < 4; ++nj)
        acc[mi][nj] = __builtin_amdgcn_mfma_f32_16x16x32_bf16(
            aF[mi], bF[nj], acc[mi][nj], 0, 0, 0);
    __builtin_amdgcn_s_setprio(0);
    // gate: next phase reads slot[(p+1)%3] -> stage(p+1) must have landed
    if (p + 2 < NT) {
      asm volatile("s_waitcnt vmcnt(4)" ::: "memory");
    } else if (p + 1 < NT) {
      asm volatile("s_waitcnt vmcnt(0)" ::: "memory");
    }
    if (p + 1 < NT) {
      __builtin_amdgcn_sched_barrier(0);
      __builtin_amdgcn_s_barrier();
      __builtin_amdgcn_sched_barrier(0);
    }
    ++cur;
    if (cur >= 3) cur = 0;
  }

  // epilogue: C/D layout col=lane&15, row=(lane>>4)*4+j
#pragma unroll
  for (int mi = 0; mi < 4; ++mi) {
    const int row = m0 + wm * 64 + mi * 16 + (l >> 4) * 4;
#pragma unroll
    for (int nj = 0; nj < 4; ++nj) {
      const int col = n0 + wn * 64 + nj * 16 + l15;
#pragma unroll
      for (int j = 0; j < 4; ++j) {
        float v = acc[mi][nj][j];
        if (EP == 0) {
          ((float*)C)[(size_t)(row + j) * N + col] = v;
        } else {
          const int cls = col >> 10;
          if (cls == 1 || cls == 2) v = fast_sigmoid(v);
          else if (cls == 3) v = fast_tanh(v);
          ((bf16*)C)[(size_t)(row + j) * N + col] = __float2bfloat16(v);
        }
      }
    }
  }
}

// ---------------------------------------------------------------------------
// Fallback fp32-B GEMM (tier-3 out-proj only)
// ---------------------------------------------------------------------------
#define BM 64
#define BN 64
#define BKK 16
__global__ __launch_bounds__(256) void gemm_nt_kernel(
    const bf16* __restrict__ A, const float* __restrict__ B,
    float* __restrict__ C, int M, int N, int K) {
  __shared__ float Asm[BKK][BM + 1];
  __shared__ float Bsm[BKK][BN + 1];
  const int n0 = blockIdx.x * BN;
  const int m0 = blockIdx.y * BM;
  const int tid = threadIdx.x;
  const int tx = tid & 15, ty = tid >> 4;
  const int lk = tid & 15, lr = tid >> 4;
  float acc[4][4] = {};
  for (int k0 = 0; k0 < K; k0 += BKK) {
#pragma unroll
    for (int p = 0; p < 4; ++p) {
      Asm[lk][lr + 16 * p] =
          __bfloat162float(A[(size_t)(m0 + lr + 16 * p) * K + (k0 + lk)]);
      Bsm[lk][lr + 16 * p] = B[(size_t)(n0 + lr + 16 * p) * K + (k0 + lk)];
    }
    __syncthreads();
#pragma unroll
    for (int kk = 0; kk < BKK; ++kk) {
      float a[4], b[4];
#pragma unroll
      for (int i = 0; i < 4; ++i) a[i] = Asm[kk][ty * 4 + i];
#pragma unroll
      for (int j = 0; j < 4; ++j) b[j] = Bsm[kk][tx * 4 + j];
#pragma unroll
      for (int i = 0; i < 4; ++i)
#pragma unroll
        for (int j = 0; j < 4; ++j) acc[i][j] += a[i] * b[j];
    }
    __syncthreads();
  }
#pragma unroll
  for (int i = 0; i < 4; ++i)
#pragma unroll
    for (int j = 0; j < 4; ++j)
      C[(size_t)(m0 + ty * 4 + i) * N + (n0 + tx * 4 + j)] = acc[i][j];
}

// ---------------------------------------------------------------------------
// Chunked scan, 8 channels/thread (16B bf16 loads)
// ---------------------------------------------------------------------------
__global__ __launch_bounds__(256) void scan_chunk_kernel(
    const bf16* __restrict__ u, float* __restrict__ cA,
    float* __restrict__ cB, int nchunk, int tchunk) {
  int idx = blockIdx.x * 256 + threadIdx.x;
  int c8 = (idx & (DD / 8 - 1)) * 8;
  int chunk = (idx / (DD / 8)) % nchunk;
  int b = idx / ((DD / 8) * nchunk);
  const bf16* ub = u + (size_t)b * TT * 4 * DD;
  float Aacc[8], Bacc[8];
#pragma unroll
  for (int j = 0; j < 8; ++j) { Aacc[j] = 1.0f; Bacc[j] = 0.0f; }
  int t0 = chunk * tchunk;
  for (int t = t0; t < t0 + tchunk; ++t) {
    const bf16* row = ub + (size_t)t * 4 * DD;
    u16x8v dv = *(const u16x8v*)(row + 2 * DD + c8);
    u16x8v iv = *(const u16x8v*)(row + 3 * DD + c8);
#pragma unroll
    for (int j = 0; j < 8; ++j) {
      float dec = b2f(dv[j]), inj = b2f(iv[j]);
      Aacc[j] *= dec;
      Bacc[j] = dec * Bacc[j] + (1.0f - dec) * inj;
    }
  }
  int base = (b * nchunk + chunk) * DD + c8;
#pragma unroll
  for (int j = 0; j < 8; ++j) { cA[base + j] = Aacc[j]; cB[base + j] = Bacc[j]; }
}

__global__ __launch_bounds__(256) void scan_prefix_kernel(
    const float* __restrict__ cA, const float* __restrict__ cB,
    float* __restrict__ S, int nchunk) {
  int idx = blockIdx.x * 256 + threadIdx.x;
  int c = idx % DD;
  int b = idx / DD;
  float s = 0.0f;
  for (int j = 0; j < nchunk; ++j) {
    int e = (b * nchunk + j) * DD + c;
    S[e] = s;
    s = cA[e] * s + cB[e];
  }
}

__global__ __launch_bounds__(256) void scan_out_kernel(
    const bf16* __restrict__ u, const float* __restrict__ S,
    bf16* __restrict__ y, int nchunk, int tchunk) {
  int idx = blockIdx.x * 256 + threadIdx.x;
  int c8 = (idx & (DD / 8 - 1)) * 8;
  int chunk = (idx / (DD / 8)) % nchunk;
  int b = idx / ((DD / 8) * nchunk);
  const bf16* ub = u + (size_t)b * TT * 4 * DD;
  bf16* yb = y + (size_t)b * TT * DD;
  float st[8];
  int sbase = (b * nchunk + chunk) * DD + c8;
#pragma unroll
  for (int j = 0; j < 8; ++j) st[j] = S[sbase + j];
  int t0 = chunk * tchunk;
  for (int t = t0; t < t0 + tchunk; ++t) {
    const bf16* row = ub + (size_t)t * 4 * DD;
    u16x8v vv = *(const u16x8v*)(row + c8);
    u16x8v gv = *(const u16x8v*)(row + DD + c8);
    u16x8v dv = *(const u16x8v*)(row + 2 * DD + c8);
    u16x8v iv = *(const u16x8v*)(row + 3 * DD + c8);
    u16x8v ov;
#pragma unroll
    for (int j = 0; j < 8; ++j) {
      float dec = b2f(dv[j]), inj = b2f(iv[j]);
      float g = b2f(gv[j]), v = b2f(vv[j]);
      st[j] = dec * st[j] + (1.0f - dec) * inj;
      ov[j] = f2b(g * v + (1.0f - g) * st[j]);
    }
    *(u16x8v*)(yb + (size_t)t * DD + c8) = ov;
  }
}

// ---------------------------------------------------------------------------
extern "C" void kernel_launch(void* const* d_in, const int* in_sizes, int n_in,
                              void* d_out, int out_size, void* d_ws,
                              size_t ws_size, hipStream_t stream) {
  const float* x = (const float*)d_in[0];
  const float* Wc = (const float*)d_in[1];
  const float* Wp = (const float*)d_in[2];
  const float* Wo = (const float*)d_in[3];
  float* out = (float*)d_out;

  const size_t nb = (size_t)TT * DD;

  auto need = [&](int nbat, int nchunk, bool wob) -> size_t {
    return (size_t)nbat * nb * 2 + (size_t)nbat * 4 * nb * 2 +
           (size_t)4 * DD * DD * 2 + (wob ? (size_t)DD * DD * 2 : 0) +
           (size_t)3 * nbat * nchunk * DD * 4;
  };

  int nbat, nchunk;
  bool haveWob;
  if (ws_size >= need(4, 64, true)) {
    nbat = 4; nchunk = 64; haveWob = true;
  } else if (ws_size >= need(1, 64, true)) {
    nbat = 1; nchunk = 64; haveWob = true;
  } else {
    nbat = 1; nchunk = 16; haveWob = false;
  }
  const int tchunk = TT / nchunk;

  char* p = (char*)d_ws;
  bf16* Wpb = (bf16*)p;  p += (size_t)4 * DD * DD * 2;
  bf16* Wob = nullptr;
  if (haveWob) { Wob = (bf16*)p; p += (size_t)DD * DD * 2; }
  bf16* xm = (bf16*)p;   p += (size_t)nbat * nb * 2;  // also y
  bf16* u = (bf16*)p;    p += (size_t)nbat * 4 * nb * 2;
  float* cA = (float*)p; p += (size_t)nbat * nchunk * DD * 4;
  float* cB = (float*)p; p += (size_t)nbat * nchunk * DD * 4;
  float* S = (float*)p;
  bf16* y = xm;

  w2bf_kernel<<<(4 * DD * DD) / 256, 256, 0, stream>>>(Wp, Wpb, 4 * DD * DD);
  if (haveWob)
    w2bf_kernel<<<(DD * DD) / 256, 256, 0, stream>>>(Wo, Wob, DD * DD);

  for (int b0 = 0; b0 < BB; b0 += nbat) {
    const float* xb = x + (size_t)b0 * nb;
    float* outb = out + (size_t)b0 * nb;
    const int Mtot = nbat * TT;
    const int total4 = (int)(nbat * nb / 4);

    conv_add_kernel<<<total4 / 256, 256, 0, stream>>>(xb, Wc, xm, total4);

    {  // u = act(xm @ Wp^T): M=Mtot, N=4096, K=1024
      const int MB = Mtot / 128, NB = 4 * DD / 128;
      const int nwg = MB * NB;
      gemm128_kernel<1><<<nwg, 256, 0, stream>>>(xm, Wpb, u, Mtot, 4 * DD, DD,
                                                 MB, NB);
    }
    {
      int nthreads = nbat * nchunk * (DD / 8);
      scan_chunk_kernel<<<nthreads / 256, 256, 0, stream>>>(u, cA, cB, nchunk,
                                                            tchunk);
      scan_prefix_kernel<<<(nbat * DD) / 256, 256, 0, stream>>>(cA, cB, S,
                                                                nchunk);
      scan_out_kernel<<<nthreads / 256, 256, 0, stream>>>(u, S, y, nchunk,
                                                          tchunk);
    }
    if (haveWob) {  // out = y @ Wo^T: M=Mtot, N=1024, K=1024
      const int MB = Mtot / 128, NB = DD / 128;
      const int nwg = MB * NB;
      gemm128_kernel<0><<<nwg, 256, 0, stream>>>(y, Wob, outb, Mtot, DD, DD,
                                                 MB, NB);
    } else {
      dim3 grid(DD / BN, Mtot / BM);
      gemm_nt_kernel<<<grid, 256, 0, stream>>>(y, Wo, outb, Mtot, DD, DD);
    }
  }
}

// Round 13
// 355.468 us; speedup vs baseline: 1.0402x; 1.0402x over previous
//
#include <hip/hip_runtime.h>
#include <hip/hip_bf16.h>
#include <math.h>

typedef __hip_bfloat16 bf16;
typedef __bf16 bf16x8 __attribute__((ext_vector_type(8)));
typedef float f32x16 __attribute__((ext_vector_type(16)));
typedef float f32x4v __attribute__((ext_vector_type(4)));
typedef unsigned short u16x8v __attribute__((ext_vector_type(8)));
typedef unsigned short u16x4v __attribute__((ext_vector_type(4)));

#define AS1 __attribute__((address_space(1)))
#define AS3 __attribute__((address_space(3)))

// Problem constants
#define BB 4
#define TT 4096
#define DD 1024

__device__ __forceinline__ float fast_sigmoid(float x) {
  return 1.0f / (1.0f + __expf(-x));
}
__device__ __forceinline__ float fast_tanh(float x) {
  return 2.0f / (1.0f + __expf(-2.0f * x)) - 1.0f;
}
__device__ __forceinline__ float b2f(unsigned short u) {
  union { unsigned int i; float f; } x;
  x.i = ((unsigned int)u) << 16;
  return x.f;
}
__device__ __forceinline__ unsigned short f2b(float f) {
  union { bf16 h; unsigned short u; } x;
  x.h = __float2bfloat16(f);
  return x.u;
}

// ---------------------------------------------------------------------------
// Weight fp32 -> bf16
// ---------------------------------------------------------------------------
__global__ __launch_bounds__(256) void w2bf_kernel(const float* __restrict__ w,
                                                   bf16* __restrict__ o,
                                                   int n) {
  int i = blockIdx.x * 256 + threadIdx.x;
  if (i < n) o[i] = __float2bfloat16(w[i]);
}

// ---------------------------------------------------------------------------
// conv + add -> bf16, 4 channels / thread
// ---------------------------------------------------------------------------
__global__ __launch_bounds__(256) void conv_add_kernel(
    const float* __restrict__ x, const float* __restrict__ Wc,
    bf16* __restrict__ xm, int total4) {
  int i = blockIdx.x * 256 + threadIdx.x;
  if (i >= total4) return;
  int c4 = (i & (DD / 4 - 1)) * 4;
  int t = (i / (DD / 4)) % TT;
  size_t base = (size_t)i * 4;
  f32x4v x0 = *(const f32x4v*)(x + base);
  f32x4v p1 = (t >= 1) ? *(const f32x4v*)(x + base - DD) : (f32x4v)0.0f;
  f32x4v p2 = (t >= 2) ? *(const f32x4v*)(x + base - 2 * DD) : (f32x4v)0.0f;
  f32x4v p3 = (t >= 3) ? *(const f32x4v*)(x + base - 3 * DD) : (f32x4v)0.0f;
  u16x4v o;
#pragma unroll
  for (int j = 0; j < 4; ++j) {
    f32x4v w = *(const f32x4v*)(Wc + (size_t)(c4 + j) * 4);
    float acc = x0[j] + w[3] * x0[j] + w[2] * p1[j] + w[1] * p2[j] +
                w[0] * p3[j];
    o[j] = f2b(acc);
  }
  *(u16x4v*)(xm + base) = o;
}

// ---------------------------------------------------------------------------
// 128x128 MFMA GEMM, BK=32, 4 waves (2Mx2N), double-buffered 32 KiB LDS --
// r10's verified best structure (217us, 0 conflicts) with the MFMA switched
// 16x16x32 -> 32x32x16 (8 instead of 16 MFMA/phase, better FLOP/cyc,
// deeper per-inst pipe to hide ds_read latency; same LDS bytes).
// Fragment layouts (m74/m101-verified): A row=l&31, k=(l>>5)*8+j;
// C/D col=l&31, row=(reg&3)+8*(reg>>2)+4*(l>>5).
// Swizzle (same involution as r10, measured 0 conflicts):
//   stage: lane l -> row l>>2, phys slot l&3; source logical slot
//          (l&3)^((l>>3)&3)
//   read:  phys slot = logical_slot ^ ((row>>1)&3); row>>1&3 == (l>>1)&3
// Per phase: 8 ds_read_b128 -> barrier -> 8 MFMA -> stage kt+2 -> vmcnt(4)
// gate -> barrier. C[m][n] = sum_k A[m][k]*B[n][k]; bf16; K%64==0,
// M,N%128==0, MB%8==0. EP=0: fp32 C. EP=1: bf16 C + per-1024-col activation.
// ---------------------------------------------------------------------------
template <int EP>
__global__ __launch_bounds__(256, 4) void gemm128_kernel(
    const bf16* __restrict__ A, const bf16* __restrict__ B,
    void* __restrict__ C, int M, int N, int K, int MB) {
  __shared__ __align__(16) bf16 As[2][128][32];
  __shared__ __align__(16) bf16 Bs[2][128][32];

  const int tid = threadIdx.x;
  const int wv = tid >> 6, l = tid & 63;
  const int wm = wv >> 1, wn = wv & 1;

  // XCD-chunked bijective block mapping (r10)
  const int bid = blockIdx.x;
  const int xcd = bid & 7, ii = bid >> 3;
  const int mb8 = MB >> 3;
  const int bm = xcd * mb8 + (ii % mb8);
  const int bn = ii / mb8;
  const int m0 = bm * 128, n0 = bn * 128;

  // staging source (pre-swizzled, r10-verified)
  const int srow = l >> 2;
  const int scolE = ((l & 3) ^ ((l >> 3) & 3)) * 8;
  const bf16* Ab = A + (size_t)(m0 + wv * 32 + srow) * K + scolE;
  const bf16* Bb = B + (size_t)(n0 + wv * 32 + srow) * K + scolE;

  // 32x32x16 frag-read constants: row = panel + mi*32 + r31,
  // logical slot = ks*2 + kh; phys = logical ^ ((row>>1)&3) = ^((l>>1)&3)
  const int r31 = l & 31;
  const int kh = l >> 5;
  const int sw = (l >> 1) & 3;
  const int ps0 = ((kh) ^ sw) * 16;       // ks=0 phys byte
  const int ps1 = ((2 + kh) ^ sw) * 16;   // ks=1 phys byte
  const char* AsB = (const char*)As;
  const char* BsB = (const char*)Bs;
  // byte base for (panel, mi): (panel*64 + mi*32 + r31) * 64
  const int aRow = (wm * 64 + r31) * 64;
  const int bRow = (wn * 64 + r31) * 64;

  auto stageKt = [&](int kt, int slot) {
    const int k0 = kt * 32;
#pragma unroll
    for (int j = 0; j < 2; ++j) {
      __builtin_amdgcn_global_load_lds(
          (const AS1 void*)(Ab + (size_t)(j * 16) * K + k0),
          (AS3 void*)&As[slot][wv * 32 + j * 16][0], 16, 0, 0);
      __builtin_amdgcn_global_load_lds(
          (const AS1 void*)(Bb + (size_t)(j * 16) * K + k0),
          (AS3 void*)&Bs[slot][wv * 32 + j * 16][0], 16, 0, 0);
    }
  };

  f32x16 acc[2][2];
#pragma unroll
  for (int i = 0; i < 2; ++i)
#pragma unroll
    for (int j = 0; j < 2; ++j) acc[i][j] = (f32x16)0.0f;

  const int NT = K >> 5;

  stageKt(0, 0);
  stageKt(1, 1);
  asm volatile("s_waitcnt vmcnt(4)" ::: "memory");  // kt0 landed
  __builtin_amdgcn_s_barrier();

  bf16x8 aF[2][2], bF[2][2];  // [mi/nj][ks]

#pragma unroll 1
  for (int t = 0; t < NT / 2; ++t) {
#pragma unroll
    for (int s = 0; s < 2; ++s) {
      const int kt = 2 * t + s;
      const int sof = s * 8192;
#pragma unroll
      for (int mi = 0; mi < 2; ++mi) {
        aF[mi][0] = *(const bf16x8*)(AsB + sof + aRow + mi * 2048 + ps0);
        aF[mi][1] = *(const bf16x8*)(AsB + sof + aRow + mi * 2048 + ps1);
      }
#pragma unroll
      for (int nj = 0; nj < 2; ++nj) {
        bF[nj][0] = *(const bf16x8*)(BsB + sof + bRow + nj * 2048 + ps0);
        bF[nj][1] = *(const bf16x8*)(BsB + sof + bRow + nj * 2048 + ps1);
      }
      __builtin_amdgcn_sched_barrier(0);
      __builtin_amdgcn_s_barrier();
      __builtin_amdgcn_s_setprio(1);
#pragma unroll
      for (int ks = 0; ks < 2; ++ks)
#pragma unroll
        for (int mi = 0; mi < 2; ++mi)
#pragma unroll
          for (int nj = 0; nj < 2; ++nj)
            acc[mi][nj] = __builtin_amdgcn_mfma_f32_32x32x16_bf16(
                aF[mi][ks], bF[nj][ks], acc[mi][nj], 0, 0, 0);
      __builtin_amdgcn_s_setprio(0);
      if (kt + 2 < NT) stageKt(kt + 2, s);
      if (kt + 1 < NT) {
        if (kt + 2 < NT)
          asm volatile("s_waitcnt vmcnt(4)" ::: "memory");
        else
          asm volatile("s_waitcnt vmcnt(0)" ::: "memory");
      }
      __builtin_amdgcn_sched_barrier(0);
      __builtin_amdgcn_s_barrier();
    }
  }

  // epilogue: C/D layout col=l&31, row=(reg&3)+8*(reg>>2)+4*kh (m74/m101)
#pragma unroll
  for (int mi = 0; mi < 2; ++mi) {
#pragma unroll
    for (int nj = 0; nj < 2; ++nj) {
      const int col = n0 + wn * 64 + nj * 32 + r31;
      const int rbase = m0 + wm * 64 + mi * 32 + 4 * kh;
#pragma unroll
      for (int reg = 0; reg < 16; ++reg) {
        const int row = rbase + (reg & 3) + 8 * (reg >> 2);
        float v = acc[mi][nj][reg];
        if (EP == 0) {
          ((float*)C)[(size_t)row * N + col] = v;
        } else {
          const int cls = col >> 10;
          if (cls == 1 || cls == 2) v = fast_sigmoid(v);
          else if (cls == 3) v = fast_tanh(v);
          ((bf16*)C)[(size_t)row * N + col] = __float2bfloat16(v);
        }
      }
    }
  }
}

// ---------------------------------------------------------------------------
// Fallback fp32-B GEMM (tier-3 out-proj only)
// ---------------------------------------------------------------------------
#define BM 64
#define BN 64
#define BKK 16
__global__ __launch_bounds__(256) void gemm_nt_kernel(
    const bf16* __restrict__ A, const float* __restrict__ B,
    float* __restrict__ C, int M, int N, int K) {
  __shared__ float Asm[BKK][BM + 1];
  __shared__ float Bsm[BKK][BN + 1];
  const int n0 = blockIdx.x * BN;
  const int m0 = blockIdx.y * BM;
  const int tid = threadIdx.x;
  const int tx = tid & 15, ty = tid >> 4;
  const int lk = tid & 15, lr = tid >> 4;
  float acc[4][4] = {};
  for (int k0 = 0; k0 < K; k0 += BKK) {
#pragma unroll
    for (int p = 0; p < 4; ++p) {
      Asm[lk][lr + 16 * p] =
          __bfloat162float(A[(size_t)(m0 + lr + 16 * p) * K + (k0 + lk)]);
      Bsm[lk][lr + 16 * p] = B[(size_t)(n0 + lr + 16 * p) * K + (k0 + lk)];
    }
    __syncthreads();
#pragma unroll
    for (int kk = 0; kk < BKK; ++kk) {
      float a[4], b[4];
#pragma unroll
      for (int i = 0; i < 4; ++i) a[i] = Asm[kk][ty * 4 + i];
#pragma unroll
      for (int j = 0; j < 4; ++j) b[j] = Bsm[kk][tx * 4 + j];
#pragma unroll
      for (int i = 0; i < 4; ++i)
#pragma unroll
        for (int j = 0; j < 4; ++j) acc[i][j] += a[i] * b[j];
    }
    __syncthreads();
  }
#pragma unroll
  for (int i = 0; i < 4; ++i)
#pragma unroll
    for (int j = 0; j < 4; ++j)
      C[(size_t)(m0 + ty * 4 + i) * N + (n0 + tx * 4 + j)] = acc[i][j];
}

// ---------------------------------------------------------------------------
// Chunked scan, 8 channels/thread (16B bf16 loads)
// ---------------------------------------------------------------------------
__global__ __launch_bounds__(256) void scan_chunk_kernel(
    const bf16* __restrict__ u, float* __restrict__ cA,
    float* __restrict__ cB, int nchunk, int tchunk) {
  int idx = blockIdx.x * 256 + threadIdx.x;
  int c8 = (idx & (DD / 8 - 1)) * 8;
  int chunk = (idx / (DD / 8)) % nchunk;
  int b = idx / ((DD / 8) * nchunk);
  const bf16* ub = u + (size_t)b * TT * 4 * DD;
  float Aacc[8], Bacc[8];
#pragma unroll
  for (int j = 0; j < 8; ++j) { Aacc[j] = 1.0f; Bacc[j] = 0.0f; }
  int t0 = chunk * tchunk;
  for (int t = t0; t < t0 + tchunk; ++t) {
    const bf16* row = ub + (size_t)t * 4 * DD;
    u16x8v dv = *(const u16x8v*)(row + 2 * DD + c8);
    u16x8v iv = *(const u16x8v*)(row + 3 * DD + c8);
#pragma unroll
    for (int j = 0; j < 8; ++j) {
      float dec = b2f(dv[j]), inj = b2f(iv[j]);
      Aacc[j] *= dec;
      Bacc[j] = dec * Bacc[j] + (1.0f - dec) * inj;
    }
  }
  int base = (b * nchunk + chunk) * DD + c8;
#pragma unroll
  for (int j = 0; j < 8; ++j) { cA[base + j] = Aacc[j]; cB[base + j] = Bacc[j]; }
}

__global__ __launch_bounds__(256) void scan_prefix_kernel(
    const float* __restrict__ cA, const float* __restrict__ cB,
    float* __restrict__ S, int nchunk) {
  int idx = blockIdx.x * 256 + threadIdx.x;
  int c = idx % DD;
  int b = idx / DD;
  float s = 0.0f;
  for (int j = 0; j < nchunk; ++j) {
    int e = (b * nchunk + j) * DD + c;
    S[e] = s;
    s = cA[e] * s + cB[e];
  }
}

__global__ __launch_bounds__(256) void scan_out_kernel(
    const bf16* __restrict__ u, const float* __restrict__ S,
    bf16* __restrict__ y, int nchunk, int tchunk) {
  int idx = blockIdx.x * 256 + threadIdx.x;
  int c8 = (idx & (DD / 8 - 1)) * 8;
  int chunk = (idx / (DD / 8)) % nchunk;
  int b = idx / ((DD / 8) * nchunk);
  const bf16* ub = u + (size_t)b * TT * 4 * DD;
  bf16* yb = y + (size_t)b * TT * DD;
  float st[8];
  int sbase = (b * nchunk + chunk) * DD + c8;
#pragma unroll
  for (int j = 0; j < 8; ++j) st[j] = S[sbase + j];
  int t0 = chunk * tchunk;
  for (int t = t0; t < t0 + tchunk; ++t) {
    const bf16* row = ub + (size_t)t * 4 * DD;
    u16x8v vv = *(const u16x8v*)(row + c8);
    u16x8v gv = *(const u16x8v*)(row + DD + c8);
    u16x8v dv = *(const u16x8v*)(row + 2 * DD + c8);
    u16x8v iv = *(const u16x8v*)(row + 3 * DD + c8);
    u16x8v ov;
#pragma unroll
    for (int j = 0; j < 8; ++j) {
      float dec = b2f(dv[j]), inj = b2f(iv[j]);
      float g = b2f(gv[j]), v = b2f(vv[j]);
      st[j] = dec * st[j] + (1.0f - dec) * inj;
      ov[j] = f2b(g * v + (1.0f - g) * st[j]);
    }
    *(u16x8v*)(yb + (size_t)t * DD + c8) = ov;
  }
}

// ---------------------------------------------------------------------------
extern "C" void kernel_launch(void* const* d_in, const int* in_sizes, int n_in,
                              void* d_out, int out_size, void* d_ws,
                              size_t ws_size, hipStream_t stream) {
  const float* x = (const float*)d_in[0];
  const float* Wc = (const float*)d_in[1];
  const float* Wp = (const float*)d_in[2];
  const float* Wo = (const float*)d_in[3];
  float* out = (float*)d_out;

  const size_t nb = (size_t)TT * DD;

  auto need = [&](int nbat, int nchunk, bool wob) -> size_t {
    return (size_t)nbat * nb * 2 + (size_t)nbat * 4 * nb * 2 +
           (size_t)4 * DD * DD * 2 + (wob ? (size_t)DD * DD * 2 : 0) +
           (size_t)3 * nbat * nchunk * DD * 4;
  };

  int nbat, nchunk;
  bool haveWob;
  if (ws_size >= need(4, 64, true)) {
    nbat = 4; nchunk = 64; haveWob = true;
  } else if (ws_size >= need(1, 64, true)) {
    nbat = 1; nchunk = 64; haveWob = true;
  } else {
    nbat = 1; nchunk = 16; haveWob = false;
  }
  const int tchunk = TT / nchunk;

  char* p = (char*)d_ws;
  bf16* Wpb = (bf16*)p;  p += (size_t)4 * DD * DD * 2;
  bf16* Wob = nullptr;
  if (haveWob) { Wob = (bf16*)p; p += (size_t)DD * DD * 2; }
  bf16* xm = (bf16*)p;   p += (size_t)nbat * nb * 2;  // also y
  bf16* u = (bf16*)p;    p += (size_t)nbat * 4 * nb * 2;
  float* cA = (float*)p; p += (size_t)nbat * nchunk * DD * 4;
  float* cB = (float*)p; p += (size_t)nbat * nchunk * DD * 4;
  float* S = (float*)p;
  bf16* y = xm;

  w2bf_kernel<<<(4 * DD * DD) / 256, 256, 0, stream>>>(Wp, Wpb, 4 * DD * DD);
  if (haveWob)
    w2bf_kernel<<<(DD * DD) / 256, 256, 0, stream>>>(Wo, Wob, DD * DD);

  for (int b0 = 0; b0 < BB; b0 += nbat) {
    const float* xb = x + (size_t)b0 * nb;
    float* outb = out + (size_t)b0 * nb;
    const int Mtot = nbat * TT;
    const int total4 = (int)(nbat * nb / 4);

    conv_add_kernel<<<total4 / 256, 256, 0, stream>>>(xb, Wc, xm, total4);

    {  // u = act(xm @ Wp^T): M=Mtot, N=4096, K=1024
      const int MB = Mtot / 128;
      const int nwg = MB * (4 * DD / 128);
      gemm128_kernel<1><<<nwg, 256, 0, stream>>>(xm, Wpb, u, Mtot, 4 * DD, DD,
                                                 MB);
    }
    {
      int nthreads = nbat * nchunk * (DD / 8);
      scan_chunk_kernel<<<nthreads / 256, 256, 0, stream>>>(u, cA, cB, nchunk,
                                                            tchunk);
      scan_prefix_kernel<<<(nbat * DD) / 256, 256, 0, stream>>>(cA, cB, S,
                                                                nchunk);
      scan_out_kernel<<<nthreads / 256, 256, 0, stream>>>(u, S, y, nchunk,
                                                          tchunk);
    }
    if (haveWob) {  // out = y @ Wo^T: M=Mtot, N=1024, K=1024
      const int MB = Mtot / 128;
      const int nwg = MB * (DD / 128);
      gemm128_kernel<0><<<nwg, 256, 0, stream>>>(y, Wob, outb, Mtot, DD, DD,
                                                 MB);
    } else {
      dim3 grid(DD / BN, Mtot / BM);
      gemm_nt_kernel<<<grid, 256, 0, stream>>>(y, Wo, outb, Mtot, DD, DD);
    }
  }
}

// Round 14
// 336.666 us; speedup vs baseline: 1.0982x; 1.0558x over previous
//
#include <hip/hip_runtime.h>
#include <hip/hip_bf16.h>
#include <math.h>

typedef __hip_bfloat16 bf16;
typedef __bf16 bf16x8 __attribute__((ext_vector_type(8)));
typedef float f32x4 __attribute__((ext_vector_type(4)));
typedef float f32x4v __attribute__((ext_vector_type(4)));
typedef unsigned short u16x8v __attribute__((ext_vector_type(8)));
typedef unsigned short u16x4v __attribute__((ext_vector_type(4)));

#define AS1 __attribute__((address_space(1)))
#define AS3 __attribute__((address_space(3)))

// Problem constants
#define BB 4
#define TT 4096
#define DD 1024

__device__ __forceinline__ float fast_sigmoid(float x) {
  return 1.0f / (1.0f + __expf(-x));
}
__device__ __forceinline__ float fast_tanh(float x) {
  return 2.0f / (1.0f + __expf(-2.0f * x)) - 1.0f;
}
__device__ __forceinline__ float b2f(unsigned short u) {
  union { unsigned int i; float f; } x;
  x.i = ((unsigned int)u) << 16;
  return x.f;
}
__device__ __forceinline__ unsigned short f2b(float f) {
  union { bf16 h; unsigned short u; } x;
  x.h = __float2bfloat16(f);
  return x.u;
}

// ---------------------------------------------------------------------------
// Weight fp32 -> bf16
// ---------------------------------------------------------------------------
__global__ __launch_bounds__(256) void w2bf_kernel(const float* __restrict__ w,
                                                   bf16* __restrict__ o,
                                                   int n) {
  int i = blockIdx.x * 256 + threadIdx.x;
  if (i < n) o[i] = __float2bfloat16(w[i]);
}

// ---------------------------------------------------------------------------
// conv + add -> bf16, 4 channels / thread
// ---------------------------------------------------------------------------
__global__ __launch_bounds__(256) void conv_add_kernel(
    const float* __restrict__ x, const float* __restrict__ Wc,
    bf16* __restrict__ xm, int total4) {
  int i = blockIdx.x * 256 + threadIdx.x;
  if (i >= total4) return;
  int c4 = (i & (DD / 4 - 1)) * 4;
  int t = (i / (DD / 4)) % TT;
  size_t base = (size_t)i * 4;
  f32x4v x0 = *(const f32x4v*)(x + base);
  f32x4v p1 = (t >= 1) ? *(const f32x4v*)(x + base - DD) : (f32x4v)0.0f;
  f32x4v p2 = (t >= 2) ? *(const f32x4v*)(x + base - 2 * DD) : (f32x4v)0.0f;
  f32x4v p3 = (t >= 3) ? *(const f32x4v*)(x + base - 3 * DD) : (f32x4v)0.0f;
  u16x4v o;
#pragma unroll
  for (int j = 0; j < 4; ++j) {
    f32x4v w = *(const f32x4v*)(Wc + (size_t)(c4 + j) * 4);
    float acc = x0[j] + w[3] * x0[j] + w[2] * p1[j] + w[1] * p2[j] +
                w[0] * p3[j];
    o[j] = f2b(acc);
  }
  *(u16x4v*)(xm + base) = o;
}

// ---------------------------------------------------------------------------
// 128x128 MFMA GEMM (r10-verified best proj structure: 217us, 0 conflicts).
// BK=32, 4 waves (2Mx2N), double-buffered 32 KiB LDS, ~4 WG/CU.
// Swizzle: stage source logical slot (l&3)^((l>>3)&3); read phys slot
// (l>>4)^((l>>1)&3)  [conflict-free, measured r10].
// Per phase: 8 ds_read_b128 -> barrier -> 16 MFMA -> stage kt+2 -> vmcnt(4)
// gate -> barrier. C[m][n] = sum_k A[m][k]*B[n][k]; bf16; K%64==0,
// M,N%128==0, MB%8==0. EP=0: fp32 C. EP=1: bf16 C + per-1024-col activation.
// ---------------------------------------------------------------------------
template <int EP>
__global__ __launch_bounds__(256, 4) void gemm128_kernel(
    const bf16* __restrict__ A, const bf16* __restrict__ B,
    void* __restrict__ C, int M, int N, int K, int MB) {
  __shared__ __align__(16) bf16 As[2][128][32];
  __shared__ __align__(16) bf16 Bs[2][128][32];

  const int tid = threadIdx.x;
  const int wv = tid >> 6, l = tid & 63;
  const int wm = wv >> 1, wn = wv & 1;

  const int bid = blockIdx.x;
  const int xcd = bid & 7, ii = bid >> 3;
  const int mb8 = MB >> 3;
  const int bm = xcd * mb8 + (ii % mb8);
  const int bn = ii / mb8;
  const int m0 = bm * 128, n0 = bn * 128;

  const int srow = l >> 2;
  const int scolE = ((l & 3) ^ ((l >> 3) & 3)) * 8;
  const bf16* Ab = A + (size_t)(m0 + wv * 32 + srow) * K + scolE;
  const bf16* Bb = B + (size_t)(n0 + wv * 32 + srow) * K + scolE;

  const int l15 = l & 15;
  const int physColB = ((l >> 4) ^ ((l >> 1) & 3)) * 16;
  const char* AsB = (const char*)As;
  const char* BsB = (const char*)Bs;
  const int aBase = wm * 4096 + l15 * 64 + physColB;
  const int bBase = wn * 4096 + l15 * 64 + physColB;

  auto stageKt = [&](int kt, int slot) {
    const int k0 = kt * 32;
#pragma unroll
    for (int j = 0; j < 2; ++j) {
      __builtin_amdgcn_global_load_lds(
          (const AS1 void*)(Ab + (size_t)(j * 16) * K + k0),
          (AS3 void*)&As[slot][wv * 32 + j * 16][0], 16, 0, 0);
      __builtin_amdgcn_global_load_lds(
          (const AS1 void*)(Bb + (size_t)(j * 16) * K + k0),
          (AS3 void*)&Bs[slot][wv * 32 + j * 16][0], 16, 0, 0);
    }
  };

  f32x4 acc[4][4];
#pragma unroll
  for (int i = 0; i < 4; ++i)
#pragma unroll
    for (int j = 0; j < 4; ++j) acc[i][j] = (f32x4)0.0f;

  const int NT = K >> 5;

  stageKt(0, 0);
  stageKt(1, 1);
  asm volatile("s_waitcnt vmcnt(4)" ::: "memory");
  __builtin_amdgcn_s_barrier();

  bf16x8 aF[4], bF[4];

#pragma unroll 1
  for (int t = 0; t < NT / 2; ++t) {
#pragma unroll
    for (int s = 0; s < 2; ++s) {
      const int kt = 2 * t + s;
      const int sof = s * 8192;
#pragma unroll
      for (int mi = 0; mi < 4; ++mi)
        aF[mi] = *(const bf16x8*)(AsB + aBase + sof + mi * 1024);
#pragma unroll
      for (int nj = 0; nj < 4; ++nj)
        bF[nj] = *(const bf16x8*)(BsB + bBase + sof + nj * 1024);
      __builtin_amdgcn_sched_barrier(0);
      __builtin_amdgcn_s_barrier();
      __builtin_amdgcn_s_setprio(1);
#pragma unroll
      for (int mi = 0; mi < 4; ++mi)
#pragma unroll
        for (int nj = 0; nj < 4; ++nj)
          acc[mi][nj] = __builtin_amdgcn_mfma_f32_16x16x32_bf16(
              aF[mi], bF[nj], acc[mi][nj], 0, 0, 0);
      __builtin_amdgcn_s_setprio(0);
      if (kt + 2 < NT) stageKt(kt + 2, s);
      if (kt + 1 < NT) {
        if (kt + 2 < NT)
          asm volatile("s_waitcnt vmcnt(4)" ::: "memory");
        else
          asm volatile("s_waitcnt vmcnt(0)" ::: "memory");
      }
      __builtin_amdgcn_sched_barrier(0);
      __builtin_amdgcn_s_barrier();
    }
  }

#pragma unroll
  for (int mi = 0; mi < 4; ++mi) {
    const int row = m0 + wm * 64 + mi * 16 + (l >> 4) * 4;
#pragma unroll
    for (int nj = 0; nj < 4; ++nj) {
      const int col = n0 + wn * 64 + nj * 16 + l15;
#pragma unroll
      for (int j = 0; j < 4; ++j) {
        float v = acc[mi][nj][j];
        if (EP == 0) {
          ((float*)C)[(size_t)(row + j) * N + col] = v;
        } else {
          const int cls = col >> 10;
          if (cls == 1 || cls == 2) v = fast_sigmoid(v);
          else if (cls == 3) v = fast_tanh(v);
          ((bf16*)C)[(size_t)(row + j) * N + col] = __float2bfloat16(v);
        }
      }
    }
  }
}

// ---------------------------------------------------------------------------
// 256x256 8-phase MFMA GEMM (r6-verified; used for the OUT projection where
// its halved A re-reads beat gemm128: out128-out256 ~= 42us from r6/r10
// totals). 512 threads = 8 waves (2Mx4N); 128 KiB LDS; lead-3 prefetch,
// vmcnt(6) gates; swizzle involution phys_slot = log ^ (row&7), staged via
// pre-swizzled global source. K%128==0, M,N%256==0, grid%8==0.
// EP=0: fp32 C. EP=1: bf16 C with per-1024-col activation.
// ---------------------------------------------------------------------------
template <int EP>
__global__ __launch_bounds__(512, 2) void gemm256_kernel(
    const bf16* __restrict__ A, const bf16* __restrict__ B,
    void* __restrict__ C, int M, int N, int K, int MB) {
  __shared__ __align__(16) bf16 As[2][2][128][64];
  __shared__ __align__(16) bf16 Bs[2][2][128][64];

  const int tid = threadIdx.x;
  const int wv = tid >> 6, l = tid & 63;
  const int wm = wv >> 2, wn = wv & 3;

  const int nwg = gridDim.x;
  const int cpx = nwg >> 3;
  const int bid = blockIdx.x;
  const int wg = (bid & 7) * cpx + (bid >> 3);
  const int bm = wg % MB, bn = wg / MB;
  const int m0 = bm * 256, n0 = bn * 256;

  const int lr3 = l >> 3;
  const int gcolE = ((l & 7) ^ (l >> 3)) * 8;
  const int l15 = l & 15;
  const int rxor = (l15 & 7) << 3;
  const int lhi8 = (l >> 4) * 8;
  const int colK0 = lhi8 ^ rxor;
  const int colK1 = (32 + lhi8) ^ rxor;

  const char* AsB = (const char*)&As[0][0][0][0];
  const char* BsB = (const char*)&Bs[0][0][0][0];
  const int aB0 = wm * 16384 + l15 * 128 + colK0 * 2;
  const int aB1 = wm * 16384 + l15 * 128 + colK1 * 2;
  const int bB0 = (wn >> 1) * 16384 + (wn & 1) * 8192 + l15 * 128 + colK0 * 2;
  const int bB1 = (wn >> 1) * 16384 + (wn & 1) * 8192 + l15 * 128 + colK1 * 2;

  const bf16* Arow = A + (size_t)(m0 + wv * 16 + lr3) * K + gcolE;
  const bf16* Brow = B + (size_t)(n0 + wv * 16 + lr3) * K + gcolE;
  const bf16* ArowH = Arow + (size_t)128 * K;
  const bf16* BrowH = Brow + (size_t)128 * K;

  bf16* AsW = &As[0][0][0][0];
  bf16* BsW = &Bs[0][0][0][0];

  auto stage1 = [&](int which, int k0) {
    const int slot = (k0 >> 6) & 1;
    const bf16* src0 =
        (which == 0 ? Brow : which == 1 ? BrowH : which == 2 ? Arow : ArowH) +
        k0;
    bf16* dst0 = (which < 2 ? BsW : AsW) + slot * 16384 + (which & 1) * 8192 +
                 wv * 1024;
#pragma unroll
    for (int j = 0; j < 2; ++j) {
      __builtin_amdgcn_global_load_lds(
          (const AS1 void*)(src0 + (size_t)(j * 8) * K),
          (AS3 void*)(dst0 + j * 512), 16, 0, 0);
    }
  };

  f32x4 acc[8][4];
#pragma unroll
  for (int i = 0; i < 8; ++i)
#pragma unroll
    for (int j = 0; j < 4; ++j) acc[i][j] = (f32x4)0.0f;

  const int NT2 = K >> 7;

  stage1(0, 0); stage1(1, 0); stage1(2, 0); stage1(3, 0);
  stage1(0, 64); stage1(1, 64); stage1(2, 64);
  asm volatile("s_waitcnt vmcnt(6)" ::: "memory");
  __builtin_amdgcn_s_barrier();

  bf16x8 aF[4][2], bF0[2][2], bF1[2][2];

  int kb = 0;
#pragma unroll 1
  for (int t = 0; t < NT2; ++t, kb += 128) {
#pragma unroll
    for (int g = 0; g < 8; ++g) {
      const int q = g & 3, grp = g >> 2;
      const int gof = grp * 32768;
      if (q == 0) {
#pragma unroll
        for (int mi = 0; mi < 4; ++mi) {
          aF[mi][0] = *(const bf16x8*)(AsB + aB0 + gof + mi * 2048);
          aF[mi][1] = *(const bf16x8*)(AsB + aB1 + gof + mi * 2048);
        }
#pragma unroll
        for (int ni = 0; ni < 2; ++ni) {
          bF0[ni][0] = *(const bf16x8*)(BsB + bB0 + gof + ni * 2048);
          bF0[ni][1] = *(const bf16x8*)(BsB + bB1 + gof + ni * 2048);
        }
      } else if (q == 1) {
#pragma unroll
        for (int ni = 0; ni < 2; ++ni) {
          bF1[ni][0] = *(const bf16x8*)(BsB + bB0 + gof + (ni + 2) * 2048);
          bF1[ni][1] = *(const bf16x8*)(BsB + bB1 + gof + (ni + 2) * 2048);
        }
      } else if (q == 2) {
#pragma unroll
        for (int mi = 0; mi < 4; ++mi) {
          aF[mi][0] = *(const bf16x8*)(AsB + aB0 + gof + (mi + 4) * 2048);
          aF[mi][1] = *(const bf16x8*)(AsB + aB1 + gof + (mi + 4) * 2048);
        }
      }
      if (t < NT2 - 1 || g == 0)
        stage1((7 + g) & 3, kb + 64 * ((7 + g) >> 2));
      __builtin_amdgcn_sched_barrier(0);
      __builtin_amdgcn_s_barrier();
      __builtin_amdgcn_s_setprio(1);
#pragma unroll
      for (int ks = 0; ks < 2; ++ks)
#pragma unroll
        for (int mi = 0; mi < 4; ++mi)
#pragma unroll
          for (int nj = 0; nj < 2; ++nj)
            acc[mi + (q >= 2 ? 4 : 0)][nj + ((q & 1) ? 2 : 0)] =
                __builtin_amdgcn_mfma_f32_16x16x32_bf16(
                    aF[mi][ks], (q & 1) ? bF1[nj][ks] : bF0[nj][ks],
                    acc[mi + (q >= 2 ? 4 : 0)][nj + ((q & 1) ? 2 : 0)], 0, 0,
                    0);
      __builtin_amdgcn_s_setprio(0);
      if (q == 3) {
        if (g == 3 && t == NT2 - 1)
          asm volatile("s_waitcnt vmcnt(0)" ::: "memory");
        else
          asm volatile("s_waitcnt vmcnt(6)" ::: "memory");
        __builtin_amdgcn_sched_barrier(0);
      }
      __builtin_amdgcn_s_barrier();
    }
  }

#pragma unroll
  for (int mi = 0; mi < 8; ++mi) {
    const int row = m0 + wm * 128 + mi * 16 + (l >> 4) * 4;
#pragma unroll
    for (int ni = 0; ni < 4; ++ni) {
      const int col = n0 + wn * 64 + ni * 16 + l15;
#pragma unroll
      for (int j = 0; j < 4; ++j) {
        float v = acc[mi][ni][j];
        if (EP == 0) {
          ((float*)C)[(size_t)(row + j) * N + col] = v;
        } else {
          const int cls = col >> 10;
          if (cls == 1 || cls == 2) v = fast_sigmoid(v);
          else if (cls == 3) v = fast_tanh(v);
          ((bf16*)C)[(size_t)(row + j) * N + col] = __float2bfloat16(v);
        }
      }
    }
  }
}

// ---------------------------------------------------------------------------
// Fallback fp32-B GEMM (tier-3 out-proj only)
// ---------------------------------------------------------------------------
#define BM 64
#define BN 64
#define BKK 16
__global__ __launch_bounds__(256) void gemm_nt_kernel(
    const bf16* __restrict__ A, const float* __restrict__ B,
    float* __restrict__ C, int M, int N, int K) {
  __shared__ float Asm[BKK][BM + 1];
  __shared__ float Bsm[BKK][BN + 1];
  const int n0 = blockIdx.x * BN;
  const int m0 = blockIdx.y * BM;
  const int tid = threadIdx.x;
  const int tx = tid & 15, ty = tid >> 4;
  const int lk = tid & 15, lr = tid >> 4;
  float acc[4][4] = {};
  for (int k0 = 0; k0 < K; k0 += BKK) {
#pragma unroll
    for (int p = 0; p < 4; ++p) {
      Asm[lk][lr + 16 * p] =
          __bfloat162float(A[(size_t)(m0 + lr + 16 * p) * K + (k0 + lk)]);
      Bsm[lk][lr + 16 * p] = B[(size_t)(n0 + lr + 16 * p) * K + (k0 + lk)];
    }
    __syncthreads();
#pragma unroll
    for (int kk = 0; kk < BKK; ++kk) {
      float a[4], b[4];
#pragma unroll
      for (int i = 0; i < 4; ++i) a[i] = Asm[kk][ty * 4 + i];
#pragma unroll
      for (int j = 0; j < 4; ++j) b[j] = Bsm[kk][tx * 4 + j];
#pragma unroll
      for (int i = 0; i < 4; ++i)
#pragma unroll
        for (int j = 0; j < 4; ++j) acc[i][j] += a[i] * b[j];
    }
    __syncthreads();
  }
#pragma unroll
  for (int i = 0; i < 4; ++i)
#pragma unroll
    for (int j = 0; j < 4; ++j)
      C[(size_t)(m0 + ty * 4 + i) * N + (n0 + tx * 4 + j)] = acc[i][j];
}

// ---------------------------------------------------------------------------
// Chunked scan, 8 channels/thread (16B bf16 loads)
// ---------------------------------------------------------------------------
__global__ __launch_bounds__(256) void scan_chunk_kernel(
    const bf16* __restrict__ u, float* __restrict__ cA,
    float* __restrict__ cB, int nchunk, int tchunk) {
  int idx = blockIdx.x * 256 + threadIdx.x;
  int c8 = (idx & (DD / 8 - 1)) * 8;
  int chunk = (idx / (DD / 8)) % nchunk;
  int b = idx / ((DD / 8) * nchunk);
  const bf16* ub = u + (size_t)b * TT * 4 * DD;
  float Aacc[8], Bacc[8];
#pragma unroll
  for (int j = 0; j < 8; ++j) { Aacc[j] = 1.0f; Bacc[j] = 0.0f; }
  int t0 = chunk * tchunk;
  for (int t = t0; t < t0 + tchunk; ++t) {
    const bf16* row = ub + (size_t)t * 4 * DD;
    u16x8v dv = *(const u16x8v*)(row + 2 * DD + c8);
    u16x8v iv = *(const u16x8v*)(row + 3 * DD + c8);
#pragma unroll
    for (int j = 0; j < 8; ++j) {
      float dec = b2f(dv[j]), inj = b2f(iv[j]);
      Aacc[j] *= dec;
      Bacc[j] = dec * Bacc[j] + (1.0f - dec) * inj;
    }
  }
  int base = (b * nchunk + chunk) * DD + c8;
#pragma unroll
  for (int j = 0; j < 8; ++j) { cA[base + j] = Aacc[j]; cB[base + j] = Bacc[j]; }
}

__global__ __launch_bounds__(256) void scan_prefix_kernel(
    const float* __restrict__ cA, const float* __restrict__ cB,
    float* __restrict__ S, int nchunk) {
  int idx = blockIdx.x * 256 + threadIdx.x;
  int c = idx % DD;
  int b = idx / DD;
  float s = 0.0f;
  for (int j = 0; j < nchunk; ++j) {
    int e = (b * nchunk + j) * DD + c;
    S[e] = s;
    s = cA[e] * s + cB[e];
  }
}

__global__ __launch_bounds__(256) void scan_out_kernel(
    const bf16* __restrict__ u, const float* __restrict__ S,
    bf16* __restrict__ y, int nchunk, int tchunk) {
  int idx = blockIdx.x * 256 + threadIdx.x;
  int c8 = (idx & (DD / 8 - 1)) * 8;
  int chunk = (idx / (DD / 8)) % nchunk;
  int b = idx / ((DD / 8) * nchunk);
  const bf16* ub = u + (size_t)b * TT * 4 * DD;
  bf16* yb = y + (size_t)b * TT * DD;
  float st[8];
  int sbase = (b * nchunk + chunk) * DD + c8;
#pragma unroll
  for (int j = 0; j < 8; ++j) st[j] = S[sbase + j];
  int t0 = chunk * tchunk;
  for (int t = t0; t < t0 + tchunk; ++t) {
    const bf16* row = ub + (size_t)t * 4 * DD;
    u16x8v vv = *(const u16x8v*)(row + c8);
    u16x8v gv = *(const u16x8v*)(row + DD + c8);
    u16x8v dv = *(const u16x8v*)(row + 2 * DD + c8);
    u16x8v iv = *(const u16x8v*)(row + 3 * DD + c8);
    u16x8v ov;
#pragma unroll
    for (int j = 0; j < 8; ++j) {
      float dec = b2f(dv[j]), inj = b2f(iv[j]);
      float g = b2f(gv[j]), v = b2f(vv[j]);
      st[j] = dec * st[j] + (1.0f - dec) * inj;
      ov[j] = f2b(g * v + (1.0f - g) * st[j]);
    }
    *(u16x8v*)(yb + (size_t)t * DD + c8) = ov;
  }
}

// ---------------------------------------------------------------------------
extern "C" void kernel_launch(void* const* d_in, const int* in_sizes, int n_in,
                              void* d_out, int out_size, void* d_ws,
                              size_t ws_size, hipStream_t stream) {
  const float* x = (const float*)d_in[0];
  const float* Wc = (const float*)d_in[1];
  const float* Wp = (const float*)d_in[2];
  const float* Wo = (const float*)d_in[3];
  float* out = (float*)d_out;

  const size_t nb = (size_t)TT * DD;

  auto need = [&](int nbat, int nchunk, bool wob) -> size_t {
    return (size_t)nbat * nb * 2 + (size_t)nbat * 4 * nb * 2 +
           (size_t)4 * DD * DD * 2 + (wob ? (size_t)DD * DD * 2 : 0) +
           (size_t)3 * nbat * nchunk * DD * 4;
  };

  int nbat, nchunk;
  bool haveWob;
  if (ws_size >= need(4, 64, true)) {
    nbat = 4; nchunk = 64; haveWob = true;
  } else if (ws_size >= need(1, 64, true)) {
    nbat = 1; nchunk = 64; haveWob = true;
  } else {
    nbat = 1; nchunk = 16; haveWob = false;
  }
  const int tchunk = TT / nchunk;

  char* p = (char*)d_ws;
  bf16* Wpb = (bf16*)p;  p += (size_t)4 * DD * DD * 2;
  bf16* Wob = nullptr;
  if (haveWob) { Wob = (bf16*)p; p += (size_t)DD * DD * 2; }
  bf16* xm = (bf16*)p;   p += (size_t)nbat * nb * 2;  // also y
  bf16* u = (bf16*)p;    p += (size_t)nbat * 4 * nb * 2;
  float* cA = (float*)p; p += (size_t)nbat * nchunk * DD * 4;
  float* cB = (float*)p; p += (size_t)nbat * nchunk * DD * 4;
  float* S = (float*)p;
  bf16* y = xm;

  w2bf_kernel<<<(4 * DD * DD) / 256, 256, 0, stream>>>(Wp, Wpb, 4 * DD * DD);
  if (haveWob)
    w2bf_kernel<<<(DD * DD) / 256, 256, 0, stream>>>(Wo, Wob, DD * DD);

  for (int b0 = 0; b0 < BB; b0 += nbat) {
    const float* xb = x + (size_t)b0 * nb;
    float* outb = out + (size_t)b0 * nb;
    const int Mtot = nbat * TT;
    const int total4 = (int)(nbat * nb / 4);

    conv_add_kernel<<<total4 / 256, 256, 0, stream>>>(xb, Wc, xm, total4);

    {  // u = act(xm @ Wp^T): M=Mtot, N=4096, K=1024  (gemm128: best proj)
      const int MB = Mtot / 128;
      const int nwg = MB * (4 * DD / 128);
      gemm128_kernel<1><<<nwg, 256, 0, stream>>>(xm, Wpb, u, Mtot, 4 * DD, DD,
                                                 MB);
    }
    {
      int nthreads = nbat * nchunk * (DD / 8);
      scan_chunk_kernel<<<nthreads / 256, 256, 0, stream>>>(u, cA, cB, nchunk,
                                                            tchunk);
      scan_prefix_kernel<<<(nbat * DD) / 256, 256, 0, stream>>>(cA, cB, S,
                                                                nchunk);
      scan_out_kernel<<<nthreads / 256, 256, 0, stream>>>(u, S, y, nchunk,
                                                          tchunk);
    }
    if (haveWob) {  // out = y @ Wo^T: M=Mtot, N=1024, K=1024 (gemm256: best)
      const int MB = Mtot / 256;
      const int nwg = MB * (DD / 256);
      gemm256_kernel<0><<<nwg, 512, 0, stream>>>(y, Wob, outb, Mtot, DD, DD,
                                                 MB);
    } else {
      dim3 grid(DD / BN, Mtot / BM);
      gemm_nt_kernel<<<grid, 256, 0, stream>>>(y, Wo, outb, Mtot, DD, DD);
    }
  }
}